// Round 8
// baseline (126.797 us; speedup 1.0000x reference)
//
#include <hip/hip_runtime.h>

// EdgeSumAggregatorSparse: out[b, t[e], d] += msgs[b, e, d]
// B=2, D=128 hard-coded; E, N derived at launch.

typedef float f32x4 __attribute__((ext_vector_type(4)));

#define D_DIM 128
#define B_DIM 2
#define NSUB 4          // sub-counters per node (atomic contention spread)
#define MAX_SEG 64      // bucket slots per sub-counter (total cap = 256)

// ---------------------------------------------------------------- zero pass
__global__ void zero_kernel(float* __restrict__ out, size_t out_elems,
                            int* __restrict__ counts, int n_counts) {
    size_t i = (size_t)blockIdx.x * blockDim.x + threadIdx.x;
    size_t stride = (size_t)gridDim.x * blockDim.x;
    size_t nv = out_elems / 4;
    f32x4* o4 = reinterpret_cast<f32x4*>(out);
    f32x4 z = 0.f;
    for (size_t j = i; j < nv; j += stride) __builtin_nontemporal_store(z, &o4[j]);
    for (size_t j = nv * 4 + i; j < out_elems; j += stride) out[j] = 0.f;
    for (size_t j = i; j < (size_t)n_counts; j += stride) counts[j] = 0;
}

// ------------------------------------------------------------- bucket fill
// One thread per edge. counts layout: [NSUB][N]; thread picks sub-counter
// s = e & (NSUB-1), claims a slot in segment s of node t's bucket
// (bucket row = NSUB*seg ints). Cached (non-NT) bucket stores: 64B line
// holds 16 slots of one segment, written ~12x before eviction, stays
// L2/L3-resident for the gather. Segment overflow falls back to direct
// fp32 atomics into out (pre-zeroed) — correct for any input.
__global__ void bucket_fill_kernel(const int* __restrict__ targets,
                                   const float* __restrict__ msgs,
                                   float* __restrict__ out,
                                   int* __restrict__ counts,
                                   int* __restrict__ buckets,
                                   int E, int N, int seg) {
    int e = blockIdx.x * blockDim.x + threadIdx.x;
    if (e >= E) return;
    int t = __builtin_nontemporal_load(&targets[e]);
    int s = e & (NSUB - 1);
    int pos = atomicAdd(&counts[s * N + t], 1);
    if (pos < seg) {
        buckets[(size_t)t * (NSUB * seg) + s * seg + pos] = e;
    } else {
        for (int b = 0; b < B_DIM; ++b) {
            const float* src = msgs + ((size_t)b * E + e) * D_DIM;
            float* dst = out + ((size_t)b * N + t) * D_DIM;
            for (int d = 0; d < D_DIM; ++d) atomicAdd(&dst[d], src[d]);
        }
    }
}

// ------------------------------------------------------------------ gather
// One wave per node, 4 waves per 256-thread block.
// lane -> (batch = lane>>5, float4 slot q = lane&31): one wave instruction
// reads BOTH batch rows of an edge = 2 x 512B = 1KB (16B/lane).
// R7 (final ILP probe): EIGHT independent accumulator chains, 8 edges/iter,
// unroll 2 -> up to 32 x 1KB loads in flight per wave, depth-6 chains.
// Pre-committed: neutral result => random-512B DRAM ceiling, declare done.
__global__ __launch_bounds__(256) void gather_kernel(
        const float* __restrict__ msgs,
        const int* __restrict__ counts,
        const int* __restrict__ buckets,
        float* __restrict__ out,
        int E, int N, int seg) {
    int wave = threadIdx.x >> 6;
    int lane = threadIdx.x & 63;
    int n = blockIdx.x * 4 + wave;
    if (n >= N) return;
    int b = lane >> 5;    // batch
    int q = lane & 31;    // float4 slot within the 128-float row

    f32x4 acc0 = 0.f, acc1 = 0.f, acc2 = 0.f, acc3 = 0.f;
    f32x4 acc4 = 0.f, acc5 = 0.f, acc6 = 0.f, acc7 = 0.f;
    const float* base = msgs + (size_t)b * E * D_DIM;
    const int* bkrow = buckets + (size_t)n * (NSUB * seg);
    bool overflow = false;

    for (int s = 0; s < NSUB; ++s) {
        int cnt_raw = counts[s * N + n];
        int cnt = cnt_raw < seg ? cnt_raw : seg;
        overflow |= (cnt_raw > seg);
        const int* bk = bkrow + s * seg;
        for (int chunk = 0; chunk < cnt; chunk += 64) {
            int m = cnt - chunk;
            if (m > 64) m = 64;
            int my_e = (lane < m) ? bk[chunk + lane] : 0;   // coalesced stage
            int j = 0;
            #pragma unroll 2
            for (; j + 7 < m; j += 8) {
                int e0 = __shfl(my_e, j);                   // uniform -> readlane
                int e1 = __shfl(my_e, j + 1);
                int e2 = __shfl(my_e, j + 2);
                int e3 = __shfl(my_e, j + 3);
                int e4 = __shfl(my_e, j + 4);
                int e5 = __shfl(my_e, j + 5);
                int e6 = __shfl(my_e, j + 6);
                int e7 = __shfl(my_e, j + 7);
                const f32x4* r0 = reinterpret_cast<const f32x4*>(base + (size_t)e0 * D_DIM);
                const f32x4* r1 = reinterpret_cast<const f32x4*>(base + (size_t)e1 * D_DIM);
                const f32x4* r2 = reinterpret_cast<const f32x4*>(base + (size_t)e2 * D_DIM);
                const f32x4* r3 = reinterpret_cast<const f32x4*>(base + (size_t)e3 * D_DIM);
                const f32x4* r4 = reinterpret_cast<const f32x4*>(base + (size_t)e4 * D_DIM);
                const f32x4* r5 = reinterpret_cast<const f32x4*>(base + (size_t)e5 * D_DIM);
                const f32x4* r6 = reinterpret_cast<const f32x4*>(base + (size_t)e6 * D_DIM);
                const f32x4* r7 = reinterpret_cast<const f32x4*>(base + (size_t)e7 * D_DIM);
                acc0 += __builtin_nontemporal_load(&r0[q]);
                acc1 += __builtin_nontemporal_load(&r1[q]);
                acc2 += __builtin_nontemporal_load(&r2[q]);
                acc3 += __builtin_nontemporal_load(&r3[q]);
                acc4 += __builtin_nontemporal_load(&r4[q]);
                acc5 += __builtin_nontemporal_load(&r5[q]);
                acc6 += __builtin_nontemporal_load(&r6[q]);
                acc7 += __builtin_nontemporal_load(&r7[q]);
            }
            for (; j < m; ++j) {
                int e0 = __shfl(my_e, j);
                const f32x4* r0 = reinterpret_cast<const f32x4*>(base + (size_t)e0 * D_DIM);
                acc0 += __builtin_nontemporal_load(&r0[q]);
            }
        }
    }

    f32x4 acc = ((acc0 + acc1) + (acc2 + acc3)) + ((acc4 + acc5) + (acc6 + acc7));
    f32x4* o = reinterpret_cast<f32x4*>(out + ((size_t)b * N + n) * D_DIM) + q;
    if (overflow) {
        // overflow contributions already atomically added into out: RMW
        f32x4 cur = *o;
        *o = cur + acc;
    } else {
        __builtin_nontemporal_store(acc, o);   // sole writer, never re-read
    }
}

// --------------------------------------------------- fallback: pure atomics
__global__ void scatter_atomic_kernel(const float* __restrict__ msgs,
                                      const int* __restrict__ targets,
                                      float* __restrict__ out,
                                      int E, int N) {
    size_t total = (size_t)E * D_DIM;
    size_t stride = (size_t)gridDim.x * blockDim.x;
    for (size_t idx = (size_t)blockIdx.x * blockDim.x + threadIdx.x;
         idx < total; idx += stride) {
        int e = (int)(idx >> 7);
        int d = (int)(idx & (D_DIM - 1));
        int t = targets[e];
        atomicAdd(&out[((size_t)0 * N + t) * D_DIM + d],
                  msgs[((size_t)0 * E + e) * D_DIM + d]);
        atomicAdd(&out[((size_t)1 * N + t) * D_DIM + d],
                  msgs[((size_t)1 * E + e) * D_DIM + d]);
    }
}

extern "C" void kernel_launch(void* const* d_in, const int* in_sizes, int n_in,
                              void* d_out, int out_size, void* d_ws, size_t ws_size,
                              hipStream_t stream) {
    const float* msgs    = (const float*)d_in[0];
    const int*   targets = (const int*)d_in[1];
    float*       out     = (float*)d_out;

    const int E = in_sizes[1];
    const int N = out_size / (B_DIM * D_DIM);

    // workspace layout: [ counts: NSUB*N ints ][ buckets: N*NSUB*seg ints ]
    size_t ws_ints = ws_size / sizeof(int);
    long seg_l = ((long)ws_ints - (long)NSUB * N) / ((long)NSUB * (N > 0 ? N : 1));
    int seg = (int)(seg_l < 0 ? 0 : (seg_l > MAX_SEG ? MAX_SEG : seg_l));

    size_t out_elems = (size_t)out_size;

    if (seg >= 4) {
        int* counts  = (int*)d_ws;
        int* buckets = counts + (size_t)NSUB * N;

        zero_kernel<<<2048, 256, 0, stream>>>(out, out_elems, counts, NSUB * N);
        bucket_fill_kernel<<<(E + 255) / 256, 256, 0, stream>>>(
            targets, msgs, out, counts, buckets, E, N, seg);
        gather_kernel<<<(N + 3) / 4, 256, 0, stream>>>(
            msgs, counts, buckets, out, E, N, seg);
    } else {
        // tiny-workspace fallback: correctness over speed
        int* counts = (int*)d_ws;  // unused
        zero_kernel<<<2048, 256, 0, stream>>>(out, out_elems, counts, 0);
        scatter_atomic_kernel<<<4096, 256, 0, stream>>>(msgs, targets, out, E, N);
    }
}

// Round 9
// 123.516 us; speedup vs baseline: 1.0266x; 1.0266x over previous
//
#include <hip/hip_runtime.h>

// EdgeSumAggregatorSparse: out[b, t[e], d] += msgs[b, e, d]
// B=2, D=128 hard-coded; E, N derived at launch.
//
// Final structure (R6 config, best measured = 123.1 us):
//   zero -> bucket_fill (segmented counting buckets, cached stores)
//        -> gather (1 wave/node, 1KB-wide reads, 4 independent acc chains,
//           NT loads/stores on single-use streams)
// ILP ladder measured: 1 chain 144.7 / 2 chains 127.4 / 4 chains 123.1 /
// 8 chains 126.8 -> 4 chains is the optimum; gather runs at ~83% of
// streaming BW on randomly-ordered 512B granules (DRAM-granule ceiling).

typedef float f32x4 __attribute__((ext_vector_type(4)));

#define D_DIM 128
#define B_DIM 2
#define NSUB 4          // sub-counters per node (atomic contention spread)
#define MAX_SEG 64      // bucket slots per sub-counter (total cap = 256)

// ---------------------------------------------------------------- zero pass
__global__ void zero_kernel(float* __restrict__ out, size_t out_elems,
                            int* __restrict__ counts, int n_counts) {
    size_t i = (size_t)blockIdx.x * blockDim.x + threadIdx.x;
    size_t stride = (size_t)gridDim.x * blockDim.x;
    size_t nv = out_elems / 4;
    f32x4* o4 = reinterpret_cast<f32x4*>(out);
    f32x4 z = 0.f;
    for (size_t j = i; j < nv; j += stride) __builtin_nontemporal_store(z, &o4[j]);
    for (size_t j = nv * 4 + i; j < out_elems; j += stride) out[j] = 0.f;
    for (size_t j = i; j < (size_t)n_counts; j += stride) counts[j] = 0;
}

// ------------------------------------------------------------- bucket fill
// One thread per edge. counts layout: [NSUB][N]; thread picks sub-counter
// s = e & (NSUB-1), claims a slot in segment s of node t's bucket
// (bucket row = NSUB*seg ints). Cached (non-NT) bucket stores: 64B line
// holds 16 slots of one segment, written ~12x before eviction, stays
// L2/L3-resident for the gather. Segment overflow falls back to direct
// fp32 atomics into out (pre-zeroed) — correct for any input.
__global__ void bucket_fill_kernel(const int* __restrict__ targets,
                                   const float* __restrict__ msgs,
                                   float* __restrict__ out,
                                   int* __restrict__ counts,
                                   int* __restrict__ buckets,
                                   int E, int N, int seg) {
    int e = blockIdx.x * blockDim.x + threadIdx.x;
    if (e >= E) return;
    int t = __builtin_nontemporal_load(&targets[e]);
    int s = e & (NSUB - 1);
    int pos = atomicAdd(&counts[s * N + t], 1);
    if (pos < seg) {
        buckets[(size_t)t * (NSUB * seg) + s * seg + pos] = e;
    } else {
        for (int b = 0; b < B_DIM; ++b) {
            const float* src = msgs + ((size_t)b * E + e) * D_DIM;
            float* dst = out + ((size_t)b * N + t) * D_DIM;
            for (int d = 0; d < D_DIM; ++d) atomicAdd(&dst[d], src[d]);
        }
    }
}

// ------------------------------------------------------------------ gather
// One wave per node, 4 waves per 256-thread block.
// lane -> (batch = lane>>5, float4 slot q = lane&31): one wave instruction
// reads BOTH batch rows of an edge = 2 x 512B = 1KB (16B/lane).
// FOUR independent accumulator chains, 4 edges/iter, unroll 4 -> up to
// 16 x 1KB loads in flight per wave (measured optimum of the ILP ladder).
__global__ __launch_bounds__(256) void gather_kernel(
        const float* __restrict__ msgs,
        const int* __restrict__ counts,
        const int* __restrict__ buckets,
        float* __restrict__ out,
        int E, int N, int seg) {
    int wave = threadIdx.x >> 6;
    int lane = threadIdx.x & 63;
    int n = blockIdx.x * 4 + wave;
    if (n >= N) return;
    int b = lane >> 5;    // batch
    int q = lane & 31;    // float4 slot within the 128-float row

    f32x4 acc0 = 0.f, acc1 = 0.f, acc2 = 0.f, acc3 = 0.f;
    const float* base = msgs + (size_t)b * E * D_DIM;
    const int* bkrow = buckets + (size_t)n * (NSUB * seg);
    bool overflow = false;

    for (int s = 0; s < NSUB; ++s) {
        int cnt_raw = counts[s * N + n];
        int cnt = cnt_raw < seg ? cnt_raw : seg;
        overflow |= (cnt_raw > seg);
        const int* bk = bkrow + s * seg;
        for (int chunk = 0; chunk < cnt; chunk += 64) {
            int m = cnt - chunk;
            if (m > 64) m = 64;
            int my_e = (lane < m) ? bk[chunk + lane] : 0;   // coalesced stage
            int j = 0;
            #pragma unroll 4
            for (; j + 3 < m; j += 4) {
                int e0 = __shfl(my_e, j);                   // uniform -> readlane
                int e1 = __shfl(my_e, j + 1);
                int e2 = __shfl(my_e, j + 2);
                int e3 = __shfl(my_e, j + 3);
                const f32x4* r0 = reinterpret_cast<const f32x4*>(base + (size_t)e0 * D_DIM);
                const f32x4* r1 = reinterpret_cast<const f32x4*>(base + (size_t)e1 * D_DIM);
                const f32x4* r2 = reinterpret_cast<const f32x4*>(base + (size_t)e2 * D_DIM);
                const f32x4* r3 = reinterpret_cast<const f32x4*>(base + (size_t)e3 * D_DIM);
                acc0 += __builtin_nontemporal_load(&r0[q]);
                acc1 += __builtin_nontemporal_load(&r1[q]);
                acc2 += __builtin_nontemporal_load(&r2[q]);
                acc3 += __builtin_nontemporal_load(&r3[q]);
            }
            for (; j < m; ++j) {
                int e0 = __shfl(my_e, j);
                const f32x4* r0 = reinterpret_cast<const f32x4*>(base + (size_t)e0 * D_DIM);
                acc0 += __builtin_nontemporal_load(&r0[q]);
            }
        }
    }

    f32x4 acc = (acc0 + acc1) + (acc2 + acc3);
    f32x4* o = reinterpret_cast<f32x4*>(out + ((size_t)b * N + n) * D_DIM) + q;
    if (overflow) {
        // overflow contributions already atomically added into out: RMW
        f32x4 cur = *o;
        *o = cur + acc;
    } else {
        __builtin_nontemporal_store(acc, o);   // sole writer, never re-read
    }
}

// --------------------------------------------------- fallback: pure atomics
__global__ void scatter_atomic_kernel(const float* __restrict__ msgs,
                                      const int* __restrict__ targets,
                                      float* __restrict__ out,
                                      int E, int N) {
    size_t total = (size_t)E * D_DIM;
    size_t stride = (size_t)gridDim.x * blockDim.x;
    for (size_t idx = (size_t)blockIdx.x * blockDim.x + threadIdx.x;
         idx < total; idx += stride) {
        int e = (int)(idx >> 7);
        int d = (int)(idx & (D_DIM - 1));
        int t = targets[e];
        atomicAdd(&out[((size_t)0 * N + t) * D_DIM + d],
                  msgs[((size_t)0 * E + e) * D_DIM + d]);
        atomicAdd(&out[((size_t)1 * N + t) * D_DIM + d],
                  msgs[((size_t)1 * E + e) * D_DIM + d]);
    }
}

extern "C" void kernel_launch(void* const* d_in, const int* in_sizes, int n_in,
                              void* d_out, int out_size, void* d_ws, size_t ws_size,
                              hipStream_t stream) {
    const float* msgs    = (const float*)d_in[0];
    const int*   targets = (const int*)d_in[1];
    float*       out     = (float*)d_out;

    const int E = in_sizes[1];
    const int N = out_size / (B_DIM * D_DIM);

    // workspace layout: [ counts: NSUB*N ints ][ buckets: N*NSUB*seg ints ]
    size_t ws_ints = ws_size / sizeof(int);
    long seg_l = ((long)ws_ints - (long)NSUB * N) / ((long)NSUB * (N > 0 ? N : 1));
    int seg = (int)(seg_l < 0 ? 0 : (seg_l > MAX_SEG ? MAX_SEG : seg_l));

    size_t out_elems = (size_t)out_size;

    if (seg >= 4) {
        int* counts  = (int*)d_ws;
        int* buckets = counts + (size_t)NSUB * N;

        zero_kernel<<<2048, 256, 0, stream>>>(out, out_elems, counts, NSUB * N);
        bucket_fill_kernel<<<(E + 255) / 256, 256, 0, stream>>>(
            targets, msgs, out, counts, buckets, E, N, seg);
        gather_kernel<<<(N + 3) / 4, 256, 0, stream>>>(
            msgs, counts, buckets, out, E, N, seg);
    } else {
        // tiny-workspace fallback: correctness over speed
        int* counts = (int*)d_ws;  // unused
        zero_kernel<<<2048, 256, 0, stream>>>(out, out_elems, counts, 0);
        scatter_atomic_kernel<<<4096, 256, 0, stream>>>(msgs, targets, out, E, N);
    }
}